// Round 14
// baseline (1591.335 us; speedup 1.0000x reference)
//
#include <hip/hip_runtime.h>
#include <hip/hip_bf16.h>
#include <stdint.h>

#define DINL __device__ __forceinline__

DINL float bf2f(__hip_bfloat16 v) { return __bfloat162float(v); }
DINL __hip_bfloat16 f2bf(float v) { return __float2bfloat16(v); }
DINL float bflo(unsigned int u) { return __uint_as_float(u << 16); }
DINL float bfhi(unsigned int u) { return __uint_as_float(u & 0xffff0000u); }

DINL float loadf(float v) { return v; }
DINL float loadf(__hip_bfloat16 v) { return __bfloat162float(v); }

typedef __attribute__((ext_vector_type(8))) short bf16x8;
typedef __attribute__((ext_vector_type(4))) float f32x4;

// ---------------- ws layout ----------------
// fp32 region (float offsets):
#define O_WTE1 0         // [2][3][9][32] fp32 blocked (te1 VALU conv)   1728
#define O_WG2  1792      // [6][64]                                      384
#define O_SS   2304      // [4][256][9]  border-class emb sums           9216
#define O_INT  11520     // [4][16384] intensity                         65536
// fp32 region ends at float 77056 = byte 308224
// bf16/byte offsets:
#define BO_W2B   308224u   // w_f2 bf16 MFMA *A-fragment* layout [24][4][8][64][8]  786432 B
#define BO_TE2B 1094656u   // w_te2 bf16 [2][2][9][64][32]      147456 B
#define BO_WG1B 1242112u   // w_g1  bf16 [1][4][9][64][32]      147456 B
#define BO_WF1B 1389568u   // w_f1  bf16 [4][4][9][64][32]      589824 B (ends 1979392)
#define BO_TEX  4194304u   // tex bf16 pixel-major [4][16384][128]  16.78 MB
#define BO_F1   20971520u  // f1  bf16 pixel-major [4][16384][256]  33.55 MB
#define BO_PING 54525952u  // fp32 scratch (unused by fused diff)
#define BO_PONG 60817408u
#define BO_W    67108864u  // weights bf16 [4][24][49][16384]  154.14 MB
#define BO_T1   BO_W             // t1 bf16 pixel-major [4][16384][64] (dead before W written)
#define BO_G1   (BO_W + 16777216u)  // g1 bf16 pixel-major [4][16384][64] (dead before W written)

// ---------------- prep: weight re-layouts (bf16 MFMA blocks) + SS table ----------------
__global__ __launch_bounds__(256) void prep_kernel(
    const float* __restrict__ w_te1, const float* __restrict__ w_te2,
    const float* __restrict__ w_g1,  const float* __restrict__ w_f1,
    const float* __restrict__ w_f2,  const float* __restrict__ w_g2,
    const float* __restrict__ emb,   const int* __restrict__ labels,
    float* __restrict__ wsf)
{
  const int gid = blockIdx.x * 256 + threadIdx.x;
  const int stride = gridDim.x * 256;
  const int A0 = 1728, A1 = A0 + 393216, A2 = A1 + 73728, A3 = A2 + 73728,
            A4 = A3 + 294912, A5 = A4 + 384;
  __hip_bfloat16* w2b  = (__hip_bfloat16*)((char*)wsf + BO_W2B);
  __hip_bfloat16* te2b = (__hip_bfloat16*)((char*)wsf + BO_TE2B);
  __hip_bfloat16* g1b  = (__hip_bfloat16*)((char*)wsf + BO_WG1B);
  __hip_bfloat16* f1b  = (__hip_bfloat16*)((char*)wsf + BO_WF1B);
  for (int i = gid; i < A5; i += stride) {
    if (i < A0) {
      int s = i; int o = s / 27; int r = s - o * 27; int ic = r / 9; int t = r - ic * 9;
      wsf[O_WTE1 + (((o >> 5) * 3 + ic) * 9 + t) * 32 + (o & 31)] = w_te1[s];
    } else if (i < A1) {
      // w_f2 [1176][256] fp32 -> bf16 A-fragment layout [c24][mt4][ks8][lane64][8]
      int s = i - A0;
      int j = s & 7; int lane = (s >> 3) & 63; int ks = (s >> 9) & 7;
      int mt = (s >> 12) & 3; int c = s >> 14;
      int tap = mt * 16 + (lane & 15);
      int k = ks * 32 + (lane >> 4) * 8 + j;
      float v = (tap < 49) ? w_f2[(c * 49 + tap) * 256 + k] : 0.f;
      w2b[s] = f2bf(v);
    } else if (i < A2) {
      int s = i - A1;
      int k = s & 31; int n = (s >> 5) & 63; int u = s >> 11;
      int t = u % 9; int v = u / 9; int kc = v & 1; int ocg = v >> 1;
      te2b[s] = f2bf(w_te2[((ocg * 64 + n) * 64 + kc * 32 + k) * 9 + t]);
    } else if (i < A3) {
      int s = i - A2;
      int k = s & 31; int n = (s >> 5) & 63; int u = s >> 11;
      int t = u % 9; int kc = u / 9;
      g1b[s] = f2bf(w_g1[(n * 128 + kc * 32 + k) * 9 + t]);
    } else if (i < A4) {
      int s = i - A3;
      int k = s & 31; int n = (s >> 5) & 63; int u = s >> 11;
      int t = u % 9; int v = u / 9; int kc = v & 3; int ocg = v >> 2;
      f1b[s] = f2bf(w_f1[((ocg * 64 + n) * 256 + kc * 32 + k) * 9 + t]);
    } else {
      int s = i - A4;
      wsf[O_WG2 + s] = w_g2[s];
    }
  }
  // SS: 16 slots per (b,o); slot s sums i in [s*8, s*8+8); shfl-reduce across slots.
  if (gid < 16384) {
    const int g = gid >> 4, slot = gid & 15;
    const int b = g >> 8, o = g & 255;
    const int lab = labels[b];
    float St[9];
#pragma unroll
    for (int t = 0; t < 9; ++t) St[t] = 0.f;
#pragma unroll 2
    for (int k = 0; k < 8; ++k) {
      const int i = slot * 8 + k;
      const float e = emb[lab * 128 + i];
      const float* wr = w_f1 + (size_t)(o * 256 + 128 + i) * 9;
#pragma unroll
      for (int t = 0; t < 9; ++t) St[t] += wr[t] * e;
    }
#pragma unroll
    for (int d = 1; d < 16; d <<= 1)
#pragma unroll
      for (int t = 0; t < 9; ++t) St[t] += __shfl_xor(St[t], d, 64);
    if (slot == 0) {
#pragma unroll
      for (int ch = 0; ch < 3; ++ch)
#pragma unroll
        for (int cw = 0; cw < 3; ++cw) {
          float sum = 0.f;
#pragma unroll
          for (int t = 0; t < 9; ++t) {
            int kh = t / 3, kw = t - kh * 3;
            bool ok = !(ch == 0 && kh == 0) && !(ch == 2 && kh == 2) &&
                      !(cw == 0 && kw == 0) && !(cw == 2 && kw == 2);
            if (ok) sum += St[t];
          }
          wsf[O_SS + g * 9 + ch * 3 + cw] = sum;
        }
    }
  }
}

// ---------------- small VALU 3x3 conv (te1 only: ICH=3) ----------------
template<typename TIn, int ICH, bool PIXMAJOR>
__global__ __launch_bounds__(256, 2) void conv3x3_kernel(
    const TIn* __restrict__ in, const float* __restrict__ wf,
    const float* __restrict__ bias,
    __hip_bfloat16* __restrict__ out, const int och_total)
{
  constexpr int CH = (ICH < 16) ? ICH : 16;
  constexpr int NCHUNK = ICH / CH;
  __shared__ TIn sIn[CH][18][20];
  const int tid = threadIdx.x;
  const int b = blockIdx.z;
  const int ob = blockIdx.y;
  const int och0 = ob * 32;
  const int tileY = blockIdx.x >> 3, tileX = blockIdx.x & 7;
  const int ty = tid >> 4, tx = tid & 15;
  const int h = tileY * 16 + ty, w = tileX * 16 + tx;
  const int h0 = tileY * 16 - 1, w0 = tileX * 16 - 1;

  float acc[32];
#pragma unroll
  for (int o = 0; o < 32; ++o) acc[o] = bias[och0 + o];

  for (int cc = 0; cc < NCHUNK; ++cc) {
    if (cc) __syncthreads();
    for (int e = tid; e < CH * 324; e += 256) {
      int ic = e / 324, r = e - ic * 324;
      int y = r / 18, x = r - y * 18;
      int gh = h0 + y, gw = w0 + x;
      TIn v = TIn(0.f);
      if ((unsigned)gh < 128u && (unsigned)gw < 128u)
        v = in[((b * ICH + cc * CH + ic) << 14) + (gh << 7) + gw];
      sIn[ic][y][x] = v;
    }
    __syncthreads();
#pragma unroll 1
    for (int ic = 0; ic < CH; ++ic) {
      const float* wrow = wf + (ob * ICH + cc * CH + ic) * 288;  // [9][32]
#pragma unroll
      for (int t = 0; t < 9; ++t) {
        const int kh = t / 3, kw = t - kh * 3;
        const float v = loadf(sIn[ic][ty + kh][tx + kw]);
#pragma unroll
        for (int o = 0; o < 32; ++o)
          acc[o] = fmaf(wrow[t * 32 + o], v, acc[o]);
      }
    }
  }

  const int pix = (h << 7) + w;
  if constexpr (!PIXMAJOR) {
#pragma unroll
    for (int o = 0; o < 32; ++o)
      out[((b * och_total + och0 + o) << 14) + pix] = f2bf(fmaxf(acc[o], 0.f));
  } else {
    union { uint4 u4[4]; __hip_bfloat16 hh[32]; } pk;
#pragma unroll
    for (int o = 0; o < 32; ++o) pk.hh[o] = f2bf(fmaxf(acc[o], 0.f));
    uint4* dst = reinterpret_cast<uint4*>(out + ((size_t)(b << 14) + pix) * och_total + och0);
#pragma unroll
    for (int i = 0; i < 4; ++i) dst[i] = pk.u4[i];
  }
}

// ---------------- MFMA implicit-GEMM 3x3 conv (zero pad), pixel-major bf16 ----------------
template<int ICH, bool ADD_SS>
__global__ __launch_bounds__(256, 2) void conv3x3_mfma_kernel(
    const __hip_bfloat16* __restrict__ in, const __hip_bfloat16* __restrict__ wb,
    const float* __restrict__ bias, const float* __restrict__ SS,
    __hip_bfloat16* __restrict__ out, const int och_total)
{
  constexpr int NKC = ICH / 32;
  __shared__ __hip_bfloat16 sH[324][40];    // (y*18+x) halo pos x 32k
  __shared__ __hip_bfloat16 sW[9][64][40];  // tap x n(och) x 32k
  const int tid = threadIdx.x, b = blockIdx.z, ocg = blockIdx.y;
  const int tileY = blockIdx.x >> 3, tileX = blockIdx.x & 7;
  const int h0 = tileY * 16 - 1, w0 = tileX * 16 - 1;
  const int wave = tid >> 6, lane = tid & 63, m16 = lane & 15, quad = lane >> 4;

  f32x4 acc[4][4];
#pragma unroll
  for (int i = 0; i < 4; ++i)
#pragma unroll
    for (int j = 0; j < 4; ++j) acc[i][j] = f32x4{0.f, 0.f, 0.f, 0.f};

  for (int kc = 0; kc < NKC; ++kc) {
    if (kc) __syncthreads();
    for (int e = tid; e < 1296; e += 256) {
      int pos = e >> 2, q = e & 3;
      int y = pos / 18, x = pos - y * 18;
      int gh = h0 + y, gw = w0 + x;
      uint4 v = uint4{0u, 0u, 0u, 0u};
      if ((unsigned)gh < 128u && (unsigned)gw < 128u)
        v = *(const uint4*)(in + ((size_t)((b << 14) + (gh << 7) + gw)) * ICH + kc * 32 + q * 8);
      *(uint4*)&sH[pos][q * 8] = v;
    }
    const uint4* wsrc = (const uint4*)(wb + ((size_t)(ocg * NKC + kc)) * 9 * 64 * 32);
    for (int e = tid; e < 2304; e += 256) {
      int q = e & 3, n = (e >> 2) & 63, t = e >> 8;
      *(uint4*)&sW[t][n][q * 8] = wsrc[e];
    }
    __syncthreads();
#pragma unroll
    for (int t = 0; t < 9; ++t) {
      const int dy = t / 3, dx = t - dy * 3;
      bf16x8 bfr[4];
#pragma unroll
      for (int nt = 0; nt < 4; ++nt)
        bfr[nt] = *(const bf16x8*)&sW[t][nt * 16 + m16][quad * 8];
#pragma unroll
      for (int mi = 0; mi < 4; ++mi) {
        const int py = wave * 4 + mi;
        const bf16x8 afr = *(const bf16x8*)&sH[(py + dy) * 18 + dx + m16][quad * 8];
#pragma unroll
        for (int nt = 0; nt < 4; ++nt)
          acc[mi][nt] = __builtin_amdgcn_mfma_f32_16x16x32_bf16(afr, bfr[nt], acc[mi][nt], 0, 0, 0);
      }
    }
  }

  float bv[4];
#pragma unroll
  for (int nt = 0; nt < 4; ++nt) bv[nt] = bias[ocg * 64 + nt * 16 + m16];
#pragma unroll
  for (int mi = 0; mi < 4; ++mi) {
    const int py = wave * 4 + mi;
    const int h = tileY * 16 + py;
    const int chc = (h == 0) ? 0 : ((h == 127) ? 2 : 1);
#pragma unroll
    for (int nt = 0; nt < 4; ++nt) {
      float sr0 = 0.f, sr1 = 0.f, sr2 = 0.f;
      if constexpr (ADD_SS) {
        const float* sp = SS + ((size_t)(b << 8) + (ocg * 64 + nt * 16 + m16)) * 9;
        sr0 = sp[chc * 3 + 0]; sr1 = sp[chc * 3 + 1]; sr2 = sp[chc * 3 + 2];
      }
      const int och = ocg * 64 + nt * 16 + m16;
#pragma unroll
      for (int r = 0; r < 4; ++r) {
        const int px = quad * 4 + r;
        const int w = tileX * 16 + px;
        float v = acc[mi][nt][r] + bv[nt];
        if constexpr (ADD_SS)
          v += (w == 0) ? sr0 : ((w == 127) ? sr2 : sr1);
        v = fmaxf(v, 0.f);
        out[((size_t)((b << 14) + (h << 7) + w)) * och_total + och] = f2bf(v);
      }
    }
  }
}

// ---------------- gate 1x1 conv + sigmoid + class_gate / intensity / condition_map ----------------
__global__ __launch_bounds__(256) void gate2_kernel(
    const __hip_bfloat16* __restrict__ g1, const float* __restrict__ wg2,
    const float* __restrict__ b_g2, const int* __restrict__ labels,
    const float* __restrict__ ci,
    float* __restrict__ out_cg, float* __restrict__ out_cond,
    float* __restrict__ inten)
{
  const int b = blockIdx.y;
  const int pix = blockIdx.x * 256 + threadIdx.x;
  float acc[6];
#pragma unroll
  for (int k = 0; k < 6; ++k) acc[k] = b_g2[k];
  const uint4* gp = (const uint4*)(g1 + ((size_t)((b << 14) + pix)) * 64);
#pragma unroll
  for (int i4 = 0; i4 < 8; ++i4) {
    const uint4 q = gp[i4];
    const float v0 = bflo(q.x), v1 = bfhi(q.x), v2 = bflo(q.y), v3 = bfhi(q.y);
    const float v4 = bflo(q.z), v5 = bfhi(q.z), v6 = bflo(q.w), v7 = bfhi(q.w);
#pragma unroll
    for (int k = 0; k < 6; ++k) {
      const float* wr = wg2 + k * 64 + i4 * 8;
      acc[k] = fmaf(wr[0], v0, acc[k]); acc[k] = fmaf(wr[1], v1, acc[k]);
      acc[k] = fmaf(wr[2], v2, acc[k]); acc[k] = fmaf(wr[3], v3, acc[k]);
      acc[k] = fmaf(wr[4], v4, acc[k]); acc[k] = fmaf(wr[5], v5, acc[k]);
      acc[k] = fmaf(wr[6], v6, acc[k]); acc[k] = fmaf(wr[7], v7, acc[k]);
    }
  }
  const int lab = labels[b];
  float gate[6], gl = 0.f;
#pragma unroll
  for (int k = 0; k < 6; ++k) {
    gate[k] = 1.f / (1.f + __expf(-acc[k]));
    gl = (k == lab) ? gate[k] : gl;
  }
  const float civ = ci[lab];
  const float it = gl * civ;
#pragma unroll
  for (int k = 0; k < 6; ++k)
    out_cg[((b * 6 + k) << 14) + pix] = (k == lab) ? gate[k] : 0.f;
  inten[(b << 14) + pix] = it;
  out_cond[(b << 14) + pix] = it * gl;
}

// ---------------- fused GEMM+softmax, v6: LDS-shared A + 128 pixels/block ----------------
__global__ __launch_bounds__(256, 3) void gemm_softmax_kernel(
    const __hip_bfloat16* __restrict__ f1, const __hip_bfloat16* __restrict__ w2b,
    const float* __restrict__ b_f2, const float* __restrict__ inten,
    __hip_bfloat16* __restrict__ wout)
{
  __shared__ __hip_bfloat16 sW[2][8192];   // 2 x 16 KB: [mtl2][ks8][lane64][8]
  const int tid = threadIdx.x;
  const int pix0 = blockIdx.x * 128;
  const int c0 = blockIdx.y * 8;                 // 8 channels per block
  const int wave = tid >> 6, lane = tid & 63;
  const int n16 = lane & 15, quad = lane >> 4;
  const int p0 = pix0 + wave * 16 + n16;         // pixel group 0
  const int p1 = p0 + 64;                        // pixel group 1

  // B fragments (f1, channel-invariant): 2 pixel groups x 8 ks-steps (64 VGPR)
  bf16x8 bfr0[8], bfr1[8];
#pragma unroll
  for (int ks = 0; ks < 8; ++ks) {
    bfr0[ks] = *(const bf16x8*)(f1 + (size_t)p0 * 256 + ks * 32 + quad * 8);
    bfr1[ks] = *(const bf16x8*)(f1 + (size_t)p1 * 256 + ks * 32 + quad * 8);
  }

  const float s0v = inten[p0], s1v = inten[p1];
  const int ob0 = p0 >> 14, op0 = p0 & 16383;
  const int ob1 = p1 >> 14, op1 = p1 & 16383;

  // unit u (0..15) = channel c0+(u>>1), mt-pair (u&1): 16 KB at w2b + unit<<12 elems
#define W2U(u) ((const uint4*)(w2b + ((((size_t)c0 + ((u) >> 1)) * 4 + (((u) & 1) << 1)) << 12)))

  // prologue: stage unit 0 into buf 0
  {
    const uint4* s0 = W2U(0);
    uint4 t0[4];
#pragma unroll
    for (int j = 0; j < 4; ++j) t0[j] = s0[tid + j * 256];
    uint4* d0 = (uint4*)&sW[0][0];
#pragma unroll
    for (int j = 0; j < 4; ++j) d0[tid + j * 256] = t0[j];
  }
  __syncthreads();

#pragma unroll 1
  for (int cl = 0; cl < 8; ++cl) {
    const int c = c0 + cl;
    f32x4 ac0[4], ac1[4];
#pragma unroll
    for (int mt = 0; mt < 4; ++mt) { ac0[mt] = f32x4{0.f,0.f,0.f,0.f}; ac1[mt] = f32x4{0.f,0.f,0.f,0.f}; }

#pragma unroll
    for (int h = 0; h < 2; ++h) {
      const int u = cl * 2 + h;
      const uint4* sn = W2U(u < 15 ? u + 1 : 15);
      uint4 tn[4];
#pragma unroll
      for (int j = 0; j < 4; ++j) tn[j] = sn[tid + j * 256];

      const __hip_bfloat16* bufp = &sW[u & 1][0];
#pragma unroll
      for (int ks = 0; ks < 8; ++ks) {
        const bf16x8 a0 = *(const bf16x8*)(bufp + ((ks) * 64 + lane) * 8);
        const bf16x8 a1 = *(const bf16x8*)(bufp + ((8 + ks) * 64 + lane) * 8);
        ac0[h * 2 + 0] = __builtin_amdgcn_mfma_f32_16x16x32_bf16(a0, bfr0[ks], ac0[h * 2 + 0], 0, 0, 0);
        ac1[h * 2 + 0] = __builtin_amdgcn_mfma_f32_16x16x32_bf16(a0, bfr1[ks], ac1[h * 2 + 0], 0, 0, 0);
        ac0[h * 2 + 1] = __builtin_amdgcn_mfma_f32_16x16x32_bf16(a1, bfr0[ks], ac0[h * 2 + 1], 0, 0, 0);
        ac1[h * 2 + 1] = __builtin_amdgcn_mfma_f32_16x16x32_bf16(a1, bfr1[ks], ac1[h * 2 + 1], 0, 0, 0);
      }

      uint4* dn = (uint4*)&sW[(u + 1) & 1][0];
#pragma unroll
      for (int j = 0; j < 4; ++j) dn[tid + j * 256] = tn[j];
      __syncthreads();
    }

    // epilogue x2 pixel groups (in-place in ac*): lane holds taps {mt*16+quad*4+r}
#pragma unroll
    for (int g = 0; g < 2; ++g) {
      f32x4* ac = g ? ac1 : ac0;
      const float s = g ? s1v : s0v;
      float mx = -3.4e38f;
#pragma unroll
      for (int mt = 0; mt < 4; ++mt)
#pragma unroll
        for (int r = 0; r < 4; ++r) {
          const int tap = mt * 16 + quad * 4 + r;
          const bool ok = tap < 49;
          const float lv = ok ? (ac[mt][r] + b_f2[c * 49 + (ok ? tap : 0)]) * s : -3.4e38f;
          ac[mt][r] = lv;
          mx = fmaxf(mx, lv);
        }
      mx = fmaxf(mx, __shfl_xor(mx, 16, 64));
      mx = fmaxf(mx, __shfl_xor(mx, 32, 64));
      float sum = 0.f;
#pragma unroll
      for (int mt = 0; mt < 4; ++mt)
#pragma unroll
        for (int r = 0; r < 4; ++r) {
          const float e = __expf(ac[mt][r] - mx);   // invalid taps: exp(-inf)=0
          ac[mt][r] = e;
          sum += e;
        }
      sum += __shfl_xor(sum, 16, 64);
      sum += __shfl_xor(sum, 32, 64);
      const float rs = 1.f / sum;

      __hip_bfloat16* wo = wout + (((size_t)((g ? ob1 : ob0) * 24 + c) * 49) << 14) + (g ? op1 : op0);
#pragma unroll
      for (int mt = 0; mt < 4; ++mt)
#pragma unroll
        for (int r = 0; r < 4; ++r) {
          const int tap = mt * 16 + quad * 4 + r;
          if (tap < 49) wo[(size_t)tap << 14] = f2bf(ac[mt][r] * rs);
        }
    }
  }
#undef W2U
}

// ---------------- fused 8-step diffusion: one block per (b,c) plane ----------------
// R13 post-mortem: per-step diff re-reads the 150 MB wts stream 8x from HBM (1.2 GB,
// ~200 us at BW ceiling). Diffusion is independent per (b,c) plane; a plane (64 KB
// fp32) lives in LDS across all 8 steps, so wts HBM traffic drops ~8x (per-plane
// 1.6 MB re-read hits L2/L3). Single buffer + register staging between 2 barriers.
// Edge clamp: rows via index clamp, cols via 3-col replicated borders.
__global__ __launch_bounds__(1024, 1) void diff_fused_kernel(
    const float* __restrict__ depth, const __hip_bfloat16* __restrict__ wts,
    float* __restrict__ out)
{
  __shared__ float sL[128][136];   // cols 3..130 = data; 0..2 / 131..133 replicated edges
  const int bc = blockIdx.x;
  const int tid = threadIdx.x;
  const float* din = depth + ((size_t)bc << 14);

  // initial load (+ border replication)
#pragma unroll
  for (int i = 0; i < 16; ++i) {
    const int e = tid + i * 1024;
    const int r = e >> 7, c = e & 127;
    const float v = din[e];
    sL[r][c + 3] = v;
    if (c == 0)   { sL[r][0] = v; sL[r][1] = v; sL[r][2] = v; }
    if (c == 127) { sL[r][131] = v; sL[r][132] = v; sL[r][133] = v; }
  }
  __syncthreads();

  const __hip_bfloat16* wbase = wts + (((size_t)bc * 49) << 14);
  float acc[4][4];

#pragma unroll 1
  for (int step = 0; step < 8; ++step) {
    // compute: thread owns 4 groups of 4 consecutive pixels
#pragma unroll
    for (int g = 0; g < 4; ++g) {
      const int q = tid + g * 1024;           // pixel quad index 0..4095
      const int r = q >> 5, c0 = (q & 31) * 4;
      float a0 = 0.f, a1 = 0.f, a2 = 0.f, a3 = 0.f;
#pragma unroll
      for (int kh = 0; kh < 7; ++kh) {
        const int sr = min(max(r + kh - 3, 0), 127);
        const float* row = &sL[sr][c0];       // padded cols c0..c0+11 (16B aligned)
        float rv[12];
        *(f32x4*)&rv[0] = *(const f32x4*)(row);
        *(f32x4*)&rv[4] = *(const f32x4*)(row + 4);
        *(f32x4*)&rv[8] = *(const f32x4*)(row + 8);
#pragma unroll
        for (int kw = 0; kw < 7; ++kw) {
          const int t = kh * 7 + kw;
          const uint2 wq = *(const uint2*)(wbase + ((size_t)t << 14) + q * 4);
          a0 = fmaf(bflo(wq.x), rv[kw],     a0);
          a1 = fmaf(bfhi(wq.x), rv[kw + 1], a1);
          a2 = fmaf(bflo(wq.y), rv[kw + 2], a2);
          a3 = fmaf(bfhi(wq.y), rv[kw + 3], a3);
        }
      }
      acc[g][0] = a0; acc[g][1] = a1; acc[g][2] = a2; acc[g][3] = a3;
    }
    if (step == 7) break;                     // last step: keep results in registers
    __syncthreads();                          // all reads done
#pragma unroll
    for (int g = 0; g < 4; ++g) {
      const int q = tid + g * 1024;
      const int r = q >> 5, c0 = (q & 31) * 4;
      sL[r][c0 + 3] = acc[g][0]; sL[r][c0 + 4] = acc[g][1];
      sL[r][c0 + 5] = acc[g][2]; sL[r][c0 + 6] = acc[g][3];
      if ((q & 31) == 0)  { sL[r][0] = acc[g][0]; sL[r][1] = acc[g][0]; sL[r][2] = acc[g][0]; }
      if ((q & 31) == 31) { sL[r][131] = acc[g][3]; sL[r][132] = acc[g][3]; sL[r][133] = acc[g][3]; }
    }
    __syncthreads();                          // writes visible
  }

  float* dout = out + ((size_t)bc << 14);
#pragma unroll
  for (int g = 0; g < 4; ++g) {
    const int q = tid + g * 1024;
    *(f32x4*)(dout + q * 4) = *(f32x4*)&acc[g][0];
  }
}

// ---------------- orchestration ----------------
extern "C" void kernel_launch(void* const* d_in, const int* in_sizes, int n_in,
                              void* d_out, int out_size, void* d_ws, size_t ws_size,
                              hipStream_t stream)
{
  const float* depth = (const float*)d_in[0];
  const float* texf  = (const float*)d_in[1];
  const int*   labels= (const int*)d_in[2];
  const float* w_te1 = (const float*)d_in[3];
  const float* b_te1 = (const float*)d_in[4];
  const float* w_te2 = (const float*)d_in[5];
  const float* b_te2 = (const float*)d_in[6];
  const float* emb   = (const float*)d_in[7];
  const float* w_f1  = (const float*)d_in[8];
  const float* b_f1  = (const float*)d_in[9];
  const float* w_f2  = (const float*)d_in[10];
  const float* b_f2  = (const float*)d_in[11];
  const float* w_g1  = (const float*)d_in[12];
  const float* b_g1  = (const float*)d_in[13];
  const float* w_g2  = (const float*)d_in[14];
  const float* b_g2  = (const float*)d_in[15];
  const float* ci    = (const float*)d_in[16];

  char*  ws  = (char*)d_ws;
  float* wsf = (float*)d_ws;
  __hip_bfloat16* w2bf  = (__hip_bfloat16*)(ws + BO_W2B);
  __hip_bfloat16* te2bf = (__hip_bfloat16*)(ws + BO_TE2B);
  __hip_bfloat16* g1bf  = (__hip_bfloat16*)(ws + BO_WG1B);
  __hip_bfloat16* f1bf  = (__hip_bfloat16*)(ws + BO_WF1B);
  __hip_bfloat16* tex   = (__hip_bfloat16*)(ws + BO_TEX);
  __hip_bfloat16* f1    = (__hip_bfloat16*)(ws + BO_F1);
  __hip_bfloat16* wts   = (__hip_bfloat16*)(ws + BO_W);
  __hip_bfloat16* t1    = (__hip_bfloat16*)(ws + BO_T1);
  __hip_bfloat16* g1    = (__hip_bfloat16*)(ws + BO_G1);

  float* out      = (float*)d_out;
  float* out_enh  = out;                 // [4][24][128][128]
  float* out_cg   = out + 1572864;       // [4][6][128][128]
  float* out_cond = out + 1966080;       // [4][1][128][128]

  prep_kernel<<<512, 256, 0, stream>>>(w_te1, w_te2, w_g1, w_f1, w_f2, w_g2, emb, labels, wsf);
  conv3x3_kernel<float, 3, true><<<dim3(64, 2, 4), 256, 0, stream>>>(texf, wsf + O_WTE1, b_te1, t1, 64);
  conv3x3_mfma_kernel<64,  false><<<dim3(64, 2, 4), 256, 0, stream>>>(t1,  te2bf, b_te2, nullptr,      tex, 128);
  conv3x3_mfma_kernel<128, false><<<dim3(64, 1, 4), 256, 0, stream>>>(tex, g1bf,  b_g1,  nullptr,      g1,  64);
  gate2_kernel<<<dim3(64, 4), 256, 0, stream>>>(g1, wsf + O_WG2, b_g2, labels, ci, out_cg, out_cond, wsf + O_INT);
  conv3x3_mfma_kernel<128, true ><<<dim3(64, 4, 4), 256, 0, stream>>>(tex, f1bf,  b_f1,  wsf + O_SS,   f1,  256);
  gemm_softmax_kernel<<<dim3(512, 3), 256, 0, stream>>>(f1, w2bf, b_f2, wsf + O_INT, wts);

  diff_fused_kernel<<<96, 1024, 0, stream>>>(depth, wts, out_enh);
}

// Round 15
// 493.154 us; speedup vs baseline: 3.2268x; 3.2268x over previous
//
#include <hip/hip_runtime.h>
#include <hip/hip_bf16.h>
#include <stdint.h>

#define DINL __device__ __forceinline__

DINL float bf2f(__hip_bfloat16 v) { return __bfloat162float(v); }
DINL __hip_bfloat16 f2bf(float v) { return __float2bfloat16(v); }
DINL float bflo(unsigned int u) { return __uint_as_float(u << 16); }
DINL float bfhi(unsigned int u) { return __uint_as_float(u & 0xffff0000u); }

DINL float loadf(float v) { return v; }
DINL float loadf(__hip_bfloat16 v) { return __bfloat162float(v); }

typedef __attribute__((ext_vector_type(8))) short bf16x8;
typedef __attribute__((ext_vector_type(4))) float f32x4;

// ---------------- ws layout ----------------
// fp32 region (float offsets):
#define O_WTE1 0         // [2][3][9][32] fp32 blocked (te1 VALU conv)   1728
#define O_WG2  1792      // [6][64]                                      384
#define O_SS   2304      // [4][256][9]  border-class emb sums           9216
#define O_INT  11520     // [4][16384] intensity                         65536
// fp32 region ends at float 77056 = byte 308224
// bf16/byte offsets:
#define BO_W2B   308224u   // w_f2 bf16 MFMA *A-fragment* layout [24][4][8][64][8]  786432 B
#define BO_TE2B 1094656u   // w_te2 bf16 [2][2][9][64][32]      147456 B
#define BO_WG1B 1242112u   // w_g1  bf16 [1][4][9][64][32]      147456 B
#define BO_WF1B 1389568u   // w_f1  bf16 [4][4][9][64][32]      589824 B (ends 1979392)
#define BO_TEX  4194304u   // tex bf16 pixel-major [4][16384][128]  16.78 MB
#define BO_F1   20971520u  // f1  bf16 pixel-major [4][16384][256]  33.55 MB
#define BO_PING 54525952u  // fp32 [4*24*16384]  6.29 MB
#define BO_PONG 60817408u
#define BO_W    67108864u  // weights bf16 [4][24][49][16384]  154.14 MB
#define BO_T1   BO_W             // t1 bf16 pixel-major [4][16384][64] (dead before W written)
#define BO_G1   (BO_W + 16777216u)  // g1 bf16 pixel-major [4][16384][64] (dead before W written)

// ---------------- prep: weight re-layouts (bf16 MFMA blocks) + SS table ----------------
__global__ __launch_bounds__(256) void prep_kernel(
    const float* __restrict__ w_te1, const float* __restrict__ w_te2,
    const float* __restrict__ w_g1,  const float* __restrict__ w_f1,
    const float* __restrict__ w_f2,  const float* __restrict__ w_g2,
    const float* __restrict__ emb,   const int* __restrict__ labels,
    float* __restrict__ wsf)
{
  const int gid = blockIdx.x * 256 + threadIdx.x;
  const int stride = gridDim.x * 256;
  const int A0 = 1728, A1 = A0 + 393216, A2 = A1 + 73728, A3 = A2 + 73728,
            A4 = A3 + 294912, A5 = A4 + 384;
  __hip_bfloat16* w2b  = (__hip_bfloat16*)((char*)wsf + BO_W2B);
  __hip_bfloat16* te2b = (__hip_bfloat16*)((char*)wsf + BO_TE2B);
  __hip_bfloat16* g1b  = (__hip_bfloat16*)((char*)wsf + BO_WG1B);
  __hip_bfloat16* f1b  = (__hip_bfloat16*)((char*)wsf + BO_WF1B);
  for (int i = gid; i < A5; i += stride) {
    if (i < A0) {
      int s = i; int o = s / 27; int r = s - o * 27; int ic = r / 9; int t = r - ic * 9;
      wsf[O_WTE1 + (((o >> 5) * 3 + ic) * 9 + t) * 32 + (o & 31)] = w_te1[s];
    } else if (i < A1) {
      // w_f2 [1176][256] fp32 -> bf16 A-fragment layout [c24][mt4][ks8][lane64][8]
      int s = i - A0;
      int j = s & 7; int lane = (s >> 3) & 63; int ks = (s >> 9) & 7;
      int mt = (s >> 12) & 3; int c = s >> 14;
      int tap = mt * 16 + (lane & 15);
      int k = ks * 32 + (lane >> 4) * 8 + j;
      float v = (tap < 49) ? w_f2[(c * 49 + tap) * 256 + k] : 0.f;
      w2b[s] = f2bf(v);
    } else if (i < A2) {
      int s = i - A1;
      int k = s & 31; int n = (s >> 5) & 63; int u = s >> 11;
      int t = u % 9; int v = u / 9; int kc = v & 1; int ocg = v >> 1;
      te2b[s] = f2bf(w_te2[((ocg * 64 + n) * 64 + kc * 32 + k) * 9 + t]);
    } else if (i < A3) {
      int s = i - A2;
      int k = s & 31; int n = (s >> 5) & 63; int u = s >> 11;
      int t = u % 9; int kc = u / 9;
      g1b[s] = f2bf(w_g1[(n * 128 + kc * 32 + k) * 9 + t]);
    } else if (i < A4) {
      int s = i - A3;
      int k = s & 31; int n = (s >> 5) & 63; int u = s >> 11;
      int t = u % 9; int v = u / 9; int kc = v & 3; int ocg = v >> 2;
      f1b[s] = f2bf(w_f1[((ocg * 64 + n) * 256 + kc * 32 + k) * 9 + t]);
    } else {
      int s = i - A4;
      wsf[O_WG2 + s] = w_g2[s];
    }
  }
  // SS: 16 slots per (b,o); slot s sums i in [s*8, s*8+8); shfl-reduce across slots.
  if (gid < 16384) {
    const int g = gid >> 4, slot = gid & 15;
    const int b = g >> 8, o = g & 255;
    const int lab = labels[b];
    float St[9];
#pragma unroll
    for (int t = 0; t < 9; ++t) St[t] = 0.f;
#pragma unroll 2
    for (int k = 0; k < 8; ++k) {
      const int i = slot * 8 + k;
      const float e = emb[lab * 128 + i];
      const float* wr = w_f1 + (size_t)(o * 256 + 128 + i) * 9;
#pragma unroll
      for (int t = 0; t < 9; ++t) St[t] += wr[t] * e;
    }
#pragma unroll
    for (int d = 1; d < 16; d <<= 1)
#pragma unroll
      for (int t = 0; t < 9; ++t) St[t] += __shfl_xor(St[t], d, 64);
    if (slot == 0) {
#pragma unroll
      for (int ch = 0; ch < 3; ++ch)
#pragma unroll
        for (int cw = 0; cw < 3; ++cw) {
          float sum = 0.f;
#pragma unroll
          for (int t = 0; t < 9; ++t) {
            int kh = t / 3, kw = t - kh * 3;
            bool ok = !(ch == 0 && kh == 0) && !(ch == 2 && kh == 2) &&
                      !(cw == 0 && kw == 0) && !(cw == 2 && kw == 2);
            if (ok) sum += St[t];
          }
          wsf[O_SS + g * 9 + ch * 3 + cw] = sum;
        }
    }
  }
}

// ---------------- small VALU 3x3 conv (te1 only: ICH=3) ----------------
template<typename TIn, int ICH, bool PIXMAJOR>
__global__ __launch_bounds__(256, 2) void conv3x3_kernel(
    const TIn* __restrict__ in, const float* __restrict__ wf,
    const float* __restrict__ bias,
    __hip_bfloat16* __restrict__ out, const int och_total)
{
  constexpr int CH = (ICH < 16) ? ICH : 16;
  constexpr int NCHUNK = ICH / CH;
  __shared__ TIn sIn[CH][18][20];
  const int tid = threadIdx.x;
  const int b = blockIdx.z;
  const int ob = blockIdx.y;
  const int och0 = ob * 32;
  const int tileY = blockIdx.x >> 3, tileX = blockIdx.x & 7;
  const int ty = tid >> 4, tx = tid & 15;
  const int h = tileY * 16 + ty, w = tileX * 16 + tx;
  const int h0 = tileY * 16 - 1, w0 = tileX * 16 - 1;

  float acc[32];
#pragma unroll
  for (int o = 0; o < 32; ++o) acc[o] = bias[och0 + o];

  for (int cc = 0; cc < NCHUNK; ++cc) {
    if (cc) __syncthreads();
    for (int e = tid; e < CH * 324; e += 256) {
      int ic = e / 324, r = e - ic * 324;
      int y = r / 18, x = r - y * 18;
      int gh = h0 + y, gw = w0 + x;
      TIn v = TIn(0.f);
      if ((unsigned)gh < 128u && (unsigned)gw < 128u)
        v = in[((b * ICH + cc * CH + ic) << 14) + (gh << 7) + gw];
      sIn[ic][y][x] = v;
    }
    __syncthreads();
#pragma unroll 1
    for (int ic = 0; ic < CH; ++ic) {
      const float* wrow = wf + (ob * ICH + cc * CH + ic) * 288;  // [9][32]
#pragma unroll
      for (int t = 0; t < 9; ++t) {
        const int kh = t / 3, kw = t - kh * 3;
        const float v = loadf(sIn[ic][ty + kh][tx + kw]);
#pragma unroll
        for (int o = 0; o < 32; ++o)
          acc[o] = fmaf(wrow[t * 32 + o], v, acc[o]);
      }
    }
  }

  const int pix = (h << 7) + w;
  if constexpr (!PIXMAJOR) {
#pragma unroll
    for (int o = 0; o < 32; ++o)
      out[((b * och_total + och0 + o) << 14) + pix] = f2bf(fmaxf(acc[o], 0.f));
  } else {
    union { uint4 u4[4]; __hip_bfloat16 hh[32]; } pk;
#pragma unroll
    for (int o = 0; o < 32; ++o) pk.hh[o] = f2bf(fmaxf(acc[o], 0.f));
    uint4* dst = reinterpret_cast<uint4*>(out + ((size_t)(b << 14) + pix) * och_total + och0);
#pragma unroll
    for (int i = 0; i < 4; ++i) dst[i] = pk.u4[i];
  }
}

// ---------------- MFMA implicit-GEMM 3x3 conv (zero pad), pixel-major bf16 ----------------
template<int ICH, bool ADD_SS>
__global__ __launch_bounds__(256, 2) void conv3x3_mfma_kernel(
    const __hip_bfloat16* __restrict__ in, const __hip_bfloat16* __restrict__ wb,
    const float* __restrict__ bias, const float* __restrict__ SS,
    __hip_bfloat16* __restrict__ out, const int och_total)
{
  constexpr int NKC = ICH / 32;
  __shared__ __hip_bfloat16 sH[324][40];    // (y*18+x) halo pos x 32k
  __shared__ __hip_bfloat16 sW[9][64][40];  // tap x n(och) x 32k
  const int tid = threadIdx.x, b = blockIdx.z, ocg = blockIdx.y;
  const int tileY = blockIdx.x >> 3, tileX = blockIdx.x & 7;
  const int h0 = tileY * 16 - 1, w0 = tileX * 16 - 1;
  const int wave = tid >> 6, lane = tid & 63, m16 = lane & 15, quad = lane >> 4;

  f32x4 acc[4][4];
#pragma unroll
  for (int i = 0; i < 4; ++i)
#pragma unroll
    for (int j = 0; j < 4; ++j) acc[i][j] = f32x4{0.f, 0.f, 0.f, 0.f};

  for (int kc = 0; kc < NKC; ++kc) {
    if (kc) __syncthreads();
    for (int e = tid; e < 1296; e += 256) {
      int pos = e >> 2, q = e & 3;
      int y = pos / 18, x = pos - y * 18;
      int gh = h0 + y, gw = w0 + x;
      uint4 v = uint4{0u, 0u, 0u, 0u};
      if ((unsigned)gh < 128u && (unsigned)gw < 128u)
        v = *(const uint4*)(in + ((size_t)((b << 14) + (gh << 7) + gw)) * ICH + kc * 32 + q * 8);
      *(uint4*)&sH[pos][q * 8] = v;
    }
    const uint4* wsrc = (const uint4*)(wb + ((size_t)(ocg * NKC + kc)) * 9 * 64 * 32);
    for (int e = tid; e < 2304; e += 256) {
      int q = e & 3, n = (e >> 2) & 63, t = e >> 8;
      *(uint4*)&sW[t][n][q * 8] = wsrc[e];
    }
    __syncthreads();
#pragma unroll
    for (int t = 0; t < 9; ++t) {
      const int dy = t / 3, dx = t - dy * 3;
      bf16x8 bfr[4];
#pragma unroll
      for (int nt = 0; nt < 4; ++nt)
        bfr[nt] = *(const bf16x8*)&sW[t][nt * 16 + m16][quad * 8];
#pragma unroll
      for (int mi = 0; mi < 4; ++mi) {
        const int py = wave * 4 + mi;
        const bf16x8 afr = *(const bf16x8*)&sH[(py + dy) * 18 + dx + m16][quad * 8];
#pragma unroll
        for (int nt = 0; nt < 4; ++nt)
          acc[mi][nt] = __builtin_amdgcn_mfma_f32_16x16x32_bf16(afr, bfr[nt], acc[mi][nt], 0, 0, 0);
      }
    }
  }

  float bv[4];
#pragma unroll
  for (int nt = 0; nt < 4; ++nt) bv[nt] = bias[ocg * 64 + nt * 16 + m16];
#pragma unroll
  for (int mi = 0; mi < 4; ++mi) {
    const int py = wave * 4 + mi;
    const int h = tileY * 16 + py;
    const int chc = (h == 0) ? 0 : ((h == 127) ? 2 : 1);
#pragma unroll
    for (int nt = 0; nt < 4; ++nt) {
      float sr0 = 0.f, sr1 = 0.f, sr2 = 0.f;
      if constexpr (ADD_SS) {
        const float* sp = SS + ((size_t)(b << 8) + (ocg * 64 + nt * 16 + m16)) * 9;
        sr0 = sp[chc * 3 + 0]; sr1 = sp[chc * 3 + 1]; sr2 = sp[chc * 3 + 2];
      }
      const int och = ocg * 64 + nt * 16 + m16;
#pragma unroll
      for (int r = 0; r < 4; ++r) {
        const int px = quad * 4 + r;
        const int w = tileX * 16 + px;
        float v = acc[mi][nt][r] + bv[nt];
        if constexpr (ADD_SS)
          v += (w == 0) ? sr0 : ((w == 127) ? sr2 : sr1);
        v = fmaxf(v, 0.f);
        out[((size_t)((b << 14) + (h << 7) + w)) * och_total + och] = f2bf(v);
      }
    }
  }
}

// ---------------- gate 1x1 conv + sigmoid + class_gate / intensity / condition_map ----------------
__global__ __launch_bounds__(256) void gate2_kernel(
    const __hip_bfloat16* __restrict__ g1, const float* __restrict__ wg2,
    const float* __restrict__ b_g2, const int* __restrict__ labels,
    const float* __restrict__ ci,
    float* __restrict__ out_cg, float* __restrict__ out_cond,
    float* __restrict__ inten)
{
  const int b = blockIdx.y;
  const int pix = blockIdx.x * 256 + threadIdx.x;
  float acc[6];
#pragma unroll
  for (int k = 0; k < 6; ++k) acc[k] = b_g2[k];
  const uint4* gp = (const uint4*)(g1 + ((size_t)((b << 14) + pix)) * 64);
#pragma unroll
  for (int i4 = 0; i4 < 8; ++i4) {
    const uint4 q = gp[i4];
    const float v0 = bflo(q.x), v1 = bfhi(q.x), v2 = bflo(q.y), v3 = bfhi(q.y);
    const float v4 = bflo(q.z), v5 = bfhi(q.z), v6 = bflo(q.w), v7 = bfhi(q.w);
#pragma unroll
    for (int k = 0; k < 6; ++k) {
      const float* wr = wg2 + k * 64 + i4 * 8;
      acc[k] = fmaf(wr[0], v0, acc[k]); acc[k] = fmaf(wr[1], v1, acc[k]);
      acc[k] = fmaf(wr[2], v2, acc[k]); acc[k] = fmaf(wr[3], v3, acc[k]);
      acc[k] = fmaf(wr[4], v4, acc[k]); acc[k] = fmaf(wr[5], v5, acc[k]);
      acc[k] = fmaf(wr[6], v6, acc[k]); acc[k] = fmaf(wr[7], v7, acc[k]);
    }
  }
  const int lab = labels[b];
  float gate[6], gl = 0.f;
#pragma unroll
  for (int k = 0; k < 6; ++k) {
    gate[k] = 1.f / (1.f + __expf(-acc[k]));
    gl = (k == lab) ? gate[k] : gl;
  }
  const float civ = ci[lab];
  const float it = gl * civ;
#pragma unroll
  for (int k = 0; k < 6; ++k)
    out_cg[((b * 6 + k) << 14) + pix] = (k == lab) ? gate[k] : 0.f;
  inten[(b << 14) + pix] = it;
  out_cond[(b << 14) + pix] = it * gl;
}

// ---------------- fused GEMM+softmax, v7: v6 + LDS-transposed coalesced stores ----------------
// R14 note: v6's epilogue issued 32 scalar 2-B stores/thread/channel at 32 KB stride
// (4x32-B segments per wave-store). v7 stages softmax results through a bf16 LDS tile
// [49 taps][136] and stores cooperatively: uint4 per 8 pixels, 256-B contiguous rows.
__global__ __launch_bounds__(256, 3) void gemm_softmax_kernel(
    const __hip_bfloat16* __restrict__ f1, const __hip_bfloat16* __restrict__ w2b,
    const float* __restrict__ b_f2, const float* __restrict__ inten,
    __hip_bfloat16* __restrict__ wout)
{
  __shared__ __hip_bfloat16 sW[2][8192];       // 2 x 16 KB: [mtl2][ks8][lane64][8]
  __shared__ __hip_bfloat16 sT[49][136];       // softmax out: [tap][pix] (+8 pad)
  const int tid = threadIdx.x;
  const int pix0 = blockIdx.x * 128;
  const int c0 = blockIdx.y * 8;                 // 8 channels per block
  const int wave = tid >> 6, lane = tid & 63;
  const int n16 = lane & 15, quad = lane >> 4;
  const int p0 = pix0 + wave * 16 + n16;         // pixel group 0
  const int p1 = p0 + 64;                        // pixel group 1

  // B fragments (f1, channel-invariant): 2 pixel groups x 8 ks-steps (64 VGPR)
  bf16x8 bfr0[8], bfr1[8];
#pragma unroll
  for (int ks = 0; ks < 8; ++ks) {
    bfr0[ks] = *(const bf16x8*)(f1 + (size_t)p0 * 256 + ks * 32 + quad * 8);
    bfr1[ks] = *(const bf16x8*)(f1 + (size_t)p1 * 256 + ks * 32 + quad * 8);
  }

  const float s0v = inten[p0], s1v = inten[p1];
  const int ob = pix0 >> 14, op = pix0 & 16383;

  // unit u (0..15) = channel c0+(u>>1), mt-pair (u&1): 16 KB at w2b + unit<<12 elems
#define W2U(u) ((const uint4*)(w2b + ((((size_t)c0 + ((u) >> 1)) * 4 + (((u) & 1) << 1)) << 12)))

  // prologue: stage unit 0 into buf 0
  {
    const uint4* s0 = W2U(0);
    uint4 t0[4];
#pragma unroll
    for (int j = 0; j < 4; ++j) t0[j] = s0[tid + j * 256];
    uint4* d0 = (uint4*)&sW[0][0];
#pragma unroll
    for (int j = 0; j < 4; ++j) d0[tid + j * 256] = t0[j];
  }
  __syncthreads();

#pragma unroll 1
  for (int cl = 0; cl < 8; ++cl) {
    const int c = c0 + cl;
    f32x4 ac0[4], ac1[4];
#pragma unroll
    for (int mt = 0; mt < 4; ++mt) { ac0[mt] = f32x4{0.f,0.f,0.f,0.f}; ac1[mt] = f32x4{0.f,0.f,0.f,0.f}; }

#pragma unroll
    for (int h = 0; h < 2; ++h) {
      const int u = cl * 2 + h;
      const uint4* sn = W2U(u < 15 ? u + 1 : 15);
      uint4 tn[4];
#pragma unroll
      for (int j = 0; j < 4; ++j) tn[j] = sn[tid + j * 256];

      const __hip_bfloat16* bufp = &sW[u & 1][0];
#pragma unroll
      for (int ks = 0; ks < 8; ++ks) {
        const bf16x8 a0 = *(const bf16x8*)(bufp + ((ks) * 64 + lane) * 8);
        const bf16x8 a1 = *(const bf16x8*)(bufp + ((8 + ks) * 64 + lane) * 8);
        ac0[h * 2 + 0] = __builtin_amdgcn_mfma_f32_16x16x32_bf16(a0, bfr0[ks], ac0[h * 2 + 0], 0, 0, 0);
        ac1[h * 2 + 0] = __builtin_amdgcn_mfma_f32_16x16x32_bf16(a0, bfr1[ks], ac1[h * 2 + 0], 0, 0, 0);
        ac0[h * 2 + 1] = __builtin_amdgcn_mfma_f32_16x16x32_bf16(a1, bfr0[ks], ac0[h * 2 + 1], 0, 0, 0);
        ac1[h * 2 + 1] = __builtin_amdgcn_mfma_f32_16x16x32_bf16(a1, bfr1[ks], ac1[h * 2 + 1], 0, 0, 0);
      }

      uint4* dn = (uint4*)&sW[(u + 1) & 1][0];
#pragma unroll
      for (int j = 0; j < 4; ++j) dn[tid + j * 256] = tn[j];
      __syncthreads();
    }

    // softmax per pixel group (in-place in ac*), results -> sT
#pragma unroll
    for (int g = 0; g < 2; ++g) {
      f32x4* ac = g ? ac1 : ac0;
      const float s = g ? s1v : s0v;
      float mx = -3.4e38f;
#pragma unroll
      for (int mt = 0; mt < 4; ++mt)
#pragma unroll
        for (int r = 0; r < 4; ++r) {
          const int tap = mt * 16 + quad * 4 + r;
          const bool ok = tap < 49;
          const float lv = ok ? (ac[mt][r] + b_f2[c * 49 + (ok ? tap : 0)]) * s : -3.4e38f;
          ac[mt][r] = lv;
          mx = fmaxf(mx, lv);
        }
      mx = fmaxf(mx, __shfl_xor(mx, 16, 64));
      mx = fmaxf(mx, __shfl_xor(mx, 32, 64));
      float sum = 0.f;
#pragma unroll
      for (int mt = 0; mt < 4; ++mt)
#pragma unroll
        for (int r = 0; r < 4; ++r) {
          const float e = __expf(ac[mt][r] - mx);   // invalid taps: exp(-inf)=0
          ac[mt][r] = e;
          sum += e;
        }
      sum += __shfl_xor(sum, 16, 64);
      sum += __shfl_xor(sum, 32, 64);
      const float rs = 1.f / sum;

      const int px = wave * 16 + n16 + g * 64;
#pragma unroll
      for (int mt = 0; mt < 4; ++mt)
#pragma unroll
        for (int r = 0; r < 4; ++r) {
          const int tap = mt * 16 + quad * 4 + r;
          if (tap < 49) sT[tap][px] = f2bf(ac[mt][r] * rs);
        }
    }
    __syncthreads();   // sT visible

    // cooperative coalesced store: 49 taps x 128 px = 784 uint4
    __hip_bfloat16* wob = wout + (((size_t)(ob * 24 + c) * 49) << 14) + op;
    for (int e = tid; e < 784; e += 256) {
      const int tap = e >> 4, qq = e & 15;
      *(uint4*)(wob + ((size_t)tap << 14) + qq * 8) = *(const uint4*)&sT[tap][qq * 8];
    }
    // WAR on sT protected by the next channel's h-loop barriers
  }
#undef W2U
}

// ---------------- diffusion step v2: 4 pixels/thread, vectorized wt loads ----------------
__global__ __launch_bounds__(256) void diff_kernel(
    const float* __restrict__ lin, const __hip_bfloat16* __restrict__ wts,
    float* __restrict__ lout)
{
  __shared__ float sT[14][136];   // 8+6 rows, 128+6 cols (136: row 16B-aligned)
  const int bc = blockIdx.y;
  const int h0 = blockIdx.x * 8;
  const int tid = threadIdx.x;
  for (int e = tid; e < 14 * 134; e += 256) {
    int y = e / 134, x = e - y * 134;
    int gh = min(max(h0 - 3 + y, 0), 127), gw = min(max(x - 3, 0), 127);
    sT[y][x] = lin[(bc << 14) + (gh << 7) + gw];
  }
  __syncthreads();
  const int tw = (tid & 31) * 4;   // first of 4 pixels in w
  const int ty = tid >> 5;         // row 0..7
  const int h = h0 + ty;
  const __hip_bfloat16* wp = wts + (((size_t)bc * 49) << 14) + (h << 7) + tw;
  float a0 = 0.f, a1 = 0.f, a2 = 0.f, a3 = 0.f;
#pragma unroll
  for (int kh = 0; kh < 7; ++kh) {
    const float* row = &sT[ty + kh][tw];
    float r[12];
    *(f32x4*)&r[0] = *(const f32x4*)(row);
    *(f32x4*)&r[4] = *(const f32x4*)(row + 4);
    *(f32x4*)&r[8] = *(const f32x4*)(row + 8);
#pragma unroll
    for (int kw = 0; kw < 7; ++kw) {
      const int t = kh * 7 + kw;
      const uint2 wq = *(const uint2*)(wp + ((size_t)t << 14));
      a0 = fmaf(bflo(wq.x), r[kw],     a0);
      a1 = fmaf(bfhi(wq.x), r[kw + 1], a1);
      a2 = fmaf(bflo(wq.y), r[kw + 2], a2);
      a3 = fmaf(bfhi(wq.y), r[kw + 3], a3);
    }
  }
  *(f32x4*)(lout + (bc << 14) + (h << 7) + tw) = f32x4{a0, a1, a2, a3};
}

// ---------------- orchestration ----------------
extern "C" void kernel_launch(void* const* d_in, const int* in_sizes, int n_in,
                              void* d_out, int out_size, void* d_ws, size_t ws_size,
                              hipStream_t stream)
{
  const float* depth = (const float*)d_in[0];
  const float* texf  = (const float*)d_in[1];
  const int*   labels= (const int*)d_in[2];
  const float* w_te1 = (const float*)d_in[3];
  const float* b_te1 = (const float*)d_in[4];
  const float* w_te2 = (const float*)d_in[5];
  const float* b_te2 = (const float*)d_in[6];
  const float* emb   = (const float*)d_in[7];
  const float* w_f1  = (const float*)d_in[8];
  const float* b_f1  = (const float*)d_in[9];
  const float* w_f2  = (const float*)d_in[10];
  const float* b_f2  = (const float*)d_in[11];
  const float* w_g1  = (const float*)d_in[12];
  const float* b_g1  = (const float*)d_in[13];
  const float* w_g2  = (const float*)d_in[14];
  const float* b_g2  = (const float*)d_in[15];
  const float* ci    = (const float*)d_in[16];

  char*  ws  = (char*)d_ws;
  float* wsf = (float*)d_ws;
  __hip_bfloat16* w2bf  = (__hip_bfloat16*)(ws + BO_W2B);
  __hip_bfloat16* te2bf = (__hip_bfloat16*)(ws + BO_TE2B);
  __hip_bfloat16* g1bf  = (__hip_bfloat16*)(ws + BO_WG1B);
  __hip_bfloat16* f1bf  = (__hip_bfloat16*)(ws + BO_WF1B);
  __hip_bfloat16* tex   = (__hip_bfloat16*)(ws + BO_TEX);
  __hip_bfloat16* f1    = (__hip_bfloat16*)(ws + BO_F1);
  float* ping           = (float*)(ws + BO_PING);
  float* pong           = (float*)(ws + BO_PONG);
  __hip_bfloat16* wts   = (__hip_bfloat16*)(ws + BO_W);
  __hip_bfloat16* t1    = (__hip_bfloat16*)(ws + BO_T1);
  __hip_bfloat16* g1    = (__hip_bfloat16*)(ws + BO_G1);

  float* out      = (float*)d_out;
  float* out_enh  = out;                 // [4][24][128][128]
  float* out_cg   = out + 1572864;       // [4][6][128][128]
  float* out_cond = out + 1966080;       // [4][1][128][128]

  prep_kernel<<<512, 256, 0, stream>>>(w_te1, w_te2, w_g1, w_f1, w_f2, w_g2, emb, labels, wsf);
  conv3x3_kernel<float, 3, true><<<dim3(64, 2, 4), 256, 0, stream>>>(texf, wsf + O_WTE1, b_te1, t1, 64);
  conv3x3_mfma_kernel<64,  false><<<dim3(64, 2, 4), 256, 0, stream>>>(t1,  te2bf, b_te2, nullptr,      tex, 128);
  conv3x3_mfma_kernel<128, false><<<dim3(64, 1, 4), 256, 0, stream>>>(tex, g1bf,  b_g1,  nullptr,      g1,  64);
  gate2_kernel<<<dim3(64, 4), 256, 0, stream>>>(g1, wsf + O_WG2, b_g2, labels, ci, out_cg, out_cond, wsf + O_INT);
  conv3x3_mfma_kernel<128, true ><<<dim3(64, 4, 4), 256, 0, stream>>>(tex, f1bf,  b_f1,  wsf + O_SS,   f1,  256);
  gemm_softmax_kernel<<<dim3(512, 3), 256, 0, stream>>>(f1, w2bf, b_f2, wsf + O_INT, wts);

  dim3 dgrid(16, 96);
  diff_kernel<<<dgrid, 256, 0, stream>>>(depth, wts, ping);
  diff_kernel<<<dgrid, 256, 0, stream>>>(ping, wts, pong);
  diff_kernel<<<dgrid, 256, 0, stream>>>(pong, wts, ping);
  diff_kernel<<<dgrid, 256, 0, stream>>>(ping, wts, pong);
  diff_kernel<<<dgrid, 256, 0, stream>>>(pong, wts, ping);
  diff_kernel<<<dgrid, 256, 0, stream>>>(ping, wts, pong);
  diff_kernel<<<dgrid, 256, 0, stream>>>(pong, wts, ping);
  diff_kernel<<<dgrid, 256, 0, stream>>>(ping, wts, out_enh);
}

// Round 16
// 490.435 us; speedup vs baseline: 3.2447x; 1.0055x over previous
//
#include <hip/hip_runtime.h>
#include <hip/hip_bf16.h>
#include <stdint.h>

#define DINL __device__ __forceinline__

DINL float bf2f(__hip_bfloat16 v) { return __bfloat162float(v); }
DINL __hip_bfloat16 f2bf(float v) { return __float2bfloat16(v); }
DINL float bflo(unsigned int u) { return __uint_as_float(u << 16); }
DINL float bfhi(unsigned int u) { return __uint_as_float(u & 0xffff0000u); }

DINL float loadf(float v) { return v; }
DINL float loadf(__hip_bfloat16 v) { return __bfloat162float(v); }

typedef __attribute__((ext_vector_type(8))) short bf16x8;
typedef __attribute__((ext_vector_type(4))) float f32x4;

// async global->LDS DMA, 16 B per lane. LDS dest must be wave-uniform base + lane*16
// (true for all call sites: addresses are base + tid*16 + const).
DINL void gld_lds16(const void* g, void* l) {
  __builtin_amdgcn_global_load_lds(
      (const __attribute__((address_space(1))) unsigned int*)g,
      (__attribute__((address_space(3))) unsigned int*)l, 16, 0, 0);
}

// ---------------- ws layout ----------------
// fp32 region (float offsets):
#define O_WTE1 0         // [2][3][9][32] fp32 blocked (te1 VALU conv)   1728
#define O_WG2  1792      // [6][64]                                      384
#define O_SS   2304      // [4][256][9]  border-class emb sums           9216
#define O_INT  11520     // [4][16384] intensity                         65536
// fp32 region ends at float 77056 = byte 308224
// bf16/byte offsets:
#define BO_W2B   308224u   // w_f2 bf16 MFMA *A-fragment* layout [24][4][8][64][8]  786432 B
#define BO_TE2B 1094656u   // w_te2 bf16 [2][2][9][64][32]      147456 B
#define BO_WG1B 1242112u   // w_g1  bf16 [1][4][9][64][32]      147456 B
#define BO_WF1B 1389568u   // w_f1  bf16 [4][4][9][64][32]      589824 B (ends 1979392)
#define BO_TEX  4194304u   // tex bf16 pixel-major [4][16384][128]  16.78 MB
#define BO_F1   20971520u  // f1  bf16 pixel-major [4][16384][256]  33.55 MB
#define BO_PING 54525952u  // fp32 [4*24*16384]  6.29 MB
#define BO_PONG 60817408u
#define BO_W    67108864u  // weights bf16 [4][24][49][16384]  154.14 MB
#define BO_T1   BO_W             // t1 bf16 pixel-major [4][16384][64] (dead before W written)

// ---------------- prep: weight re-layouts (bf16 MFMA blocks) + SS table ----------------
__global__ __launch_bounds__(256) void prep_kernel(
    const float* __restrict__ w_te1, const float* __restrict__ w_te2,
    const float* __restrict__ w_g1,  const float* __restrict__ w_f1,
    const float* __restrict__ w_f2,  const float* __restrict__ w_g2,
    const float* __restrict__ emb,   const int* __restrict__ labels,
    float* __restrict__ wsf)
{
  const int gid = blockIdx.x * 256 + threadIdx.x;
  const int stride = gridDim.x * 256;
  const int A0 = 1728, A1 = A0 + 393216, A2 = A1 + 73728, A3 = A2 + 73728,
            A4 = A3 + 294912, A5 = A4 + 384;
  __hip_bfloat16* w2b  = (__hip_bfloat16*)((char*)wsf + BO_W2B);
  __hip_bfloat16* te2b = (__hip_bfloat16*)((char*)wsf + BO_TE2B);
  __hip_bfloat16* g1b  = (__hip_bfloat16*)((char*)wsf + BO_WG1B);
  __hip_bfloat16* f1b  = (__hip_bfloat16*)((char*)wsf + BO_WF1B);
  for (int i = gid; i < A5; i += stride) {
    if (i < A0) {
      int s = i; int o = s / 27; int r = s - o * 27; int ic = r / 9; int t = r - ic * 9;
      wsf[O_WTE1 + (((o >> 5) * 3 + ic) * 9 + t) * 32 + (o & 31)] = w_te1[s];
    } else if (i < A1) {
      // w_f2 [1176][256] fp32 -> bf16 A-fragment layout [c24][mt4][ks8][lane64][8]
      int s = i - A0;
      int j = s & 7; int lane = (s >> 3) & 63; int ks = (s >> 9) & 7;
      int mt = (s >> 12) & 3; int c = s >> 14;
      int tap = mt * 16 + (lane & 15);
      int k = ks * 32 + (lane >> 4) * 8 + j;
      float v = (tap < 49) ? w_f2[(c * 49 + tap) * 256 + k] : 0.f;
      w2b[s] = f2bf(v);
    } else if (i < A2) {
      int s = i - A1;
      int k = s & 31; int n = (s >> 5) & 63; int u = s >> 11;
      int t = u % 9; int v = u / 9; int kc = v & 1; int ocg = v >> 1;
      te2b[s] = f2bf(w_te2[((ocg * 64 + n) * 64 + kc * 32 + k) * 9 + t]);
    } else if (i < A3) {
      int s = i - A2;
      int k = s & 31; int n = (s >> 5) & 63; int u = s >> 11;
      int t = u % 9; int kc = u / 9;
      g1b[s] = f2bf(w_g1[(n * 128 + kc * 32 + k) * 9 + t]);
    } else if (i < A4) {
      int s = i - A3;
      int k = s & 31; int n = (s >> 5) & 63; int u = s >> 11;
      int t = u % 9; int v = u / 9; int kc = v & 3; int ocg = v >> 2;
      f1b[s] = f2bf(w_f1[((ocg * 64 + n) * 256 + kc * 32 + k) * 9 + t]);
    } else {
      int s = i - A4;
      wsf[O_WG2 + s] = w_g2[s];
    }
  }
  // SS: 16 slots per (b,o); slot s sums i in [s*8, s*8+8); shfl-reduce across slots.
  if (gid < 16384) {
    const int g = gid >> 4, slot = gid & 15;
    const int b = g >> 8, o = g & 255;
    const int lab = labels[b];
    float St[9];
#pragma unroll
    for (int t = 0; t < 9; ++t) St[t] = 0.f;
#pragma unroll 2
    for (int k = 0; k < 8; ++k) {
      const int i = slot * 8 + k;
      const float e = emb[lab * 128 + i];
      const float* wr = w_f1 + (size_t)(o * 256 + 128 + i) * 9;
#pragma unroll
      for (int t = 0; t < 9; ++t) St[t] += wr[t] * e;
    }
#pragma unroll
    for (int d = 1; d < 16; d <<= 1)
#pragma unroll
      for (int t = 0; t < 9; ++t) St[t] += __shfl_xor(St[t], d, 64);
    if (slot == 0) {
#pragma unroll
      for (int ch = 0; ch < 3; ++ch)
#pragma unroll
        for (int cw = 0; cw < 3; ++cw) {
          float sum = 0.f;
#pragma unroll
          for (int t = 0; t < 9; ++t) {
            int kh = t / 3, kw = t - kh * 3;
            bool ok = !(ch == 0 && kh == 0) && !(ch == 2 && kh == 2) &&
                      !(cw == 0 && kw == 0) && !(cw == 2 && kw == 2);
            if (ok) sum += St[t];
          }
          wsf[O_SS + g * 9 + ch * 3 + cw] = sum;
        }
    }
  }
}

// ---------------- small VALU 3x3 conv (te1 only: ICH=3) ----------------
template<typename TIn, int ICH, bool PIXMAJOR>
__global__ __launch_bounds__(256, 2) void conv3x3_kernel(
    const TIn* __restrict__ in, const float* __restrict__ wf,
    const float* __restrict__ bias,
    __hip_bfloat16* __restrict__ out, const int och_total)
{
  constexpr int CH = (ICH < 16) ? ICH : 16;
  constexpr int NCHUNK = ICH / CH;
  __shared__ TIn sIn[CH][18][20];
  const int tid = threadIdx.x;
  const int b = blockIdx.z;
  const int ob = blockIdx.y;
  const int och0 = ob * 32;
  const int tileY = blockIdx.x >> 3, tileX = blockIdx.x & 7;
  const int ty = tid >> 4, tx = tid & 15;
  const int h = tileY * 16 + ty, w = tileX * 16 + tx;
  const int h0 = tileY * 16 - 1, w0 = tileX * 16 - 1;

  float acc[32];
#pragma unroll
  for (int o = 0; o < 32; ++o) acc[o] = bias[och0 + o];

  for (int cc = 0; cc < NCHUNK; ++cc) {
    if (cc) __syncthreads();
    for (int e = tid; e < CH * 324; e += 256) {
      int ic = e / 324, r = e - ic * 324;
      int y = r / 18, x = r - y * 18;
      int gh = h0 + y, gw = w0 + x;
      TIn v = TIn(0.f);
      if ((unsigned)gh < 128u && (unsigned)gw < 128u)
        v = in[((b * ICH + cc * CH + ic) << 14) + (gh << 7) + gw];
      sIn[ic][y][x] = v;
    }
    __syncthreads();
#pragma unroll 1
    for (int ic = 0; ic < CH; ++ic) {
      const float* wrow = wf + (ob * ICH + cc * CH + ic) * 288;  // [9][32]
#pragma unroll
      for (int t = 0; t < 9; ++t) {
        const int kh = t / 3, kw = t - kh * 3;
        const float v = loadf(sIn[ic][ty + kh][tx + kw]);
#pragma unroll
        for (int o = 0; o < 32; ++o)
          acc[o] = fmaf(wrow[t * 32 + o], v, acc[o]);
      }
    }
  }

  const int pix = (h << 7) + w;
  if constexpr (!PIXMAJOR) {
#pragma unroll
    for (int o = 0; o < 32; ++o)
      out[((b * och_total + och0 + o) << 14) + pix] = f2bf(fmaxf(acc[o], 0.f));
  } else {
    union { uint4 u4[4]; __hip_bfloat16 hh[32]; } pk;
#pragma unroll
    for (int o = 0; o < 32; ++o) pk.hh[o] = f2bf(fmaxf(acc[o], 0.f));
    uint4* dst = reinterpret_cast<uint4*>(out + ((size_t)(b << 14) + pix) * och_total + och0);
#pragma unroll
    for (int i = 0; i < 4; ++i) dst[i] = pk.u4[i];
  }
}

// ---------------- MFMA implicit-GEMM 3x3 conv (zero pad), pixel-major bf16 ----------------
// GATE=true (gate1 instance, 64 och, ocg grid = 1): fuses the former gate2_kernel —
// fragments round-trip through an LDS overlay (smem reused after the MFMA loop),
// then per-thread 64->6 dot + sigmoid + class_gate/intensity/condition writes.
// Numerics identical to the split version: g1 quantized to bf16 at the same point.
template<int ICH, bool ADD_SS, bool GATE>
__global__ __launch_bounds__(256, 2) void conv3x3_mfma_kernel(
    const __hip_bfloat16* __restrict__ in, const __hip_bfloat16* __restrict__ wb,
    const float* __restrict__ bias, const float* __restrict__ SS,
    __hip_bfloat16* __restrict__ out, const int och_total,
    const float* __restrict__ wg2, const float* __restrict__ b_g2,
    const int* __restrict__ labels, const float* __restrict__ ci,
    float* __restrict__ out_cg, float* __restrict__ out_cond,
    float* __restrict__ inten)
{
  constexpr int NKC = ICH / 32;
  __shared__ __hip_bfloat16 smem[36000];   // sH 324*40 | sW 9*64*40  (72 KB)
#define SHX(pos, k) smem[(pos) * 40 + (k)]
#define SWX(t, n, k) smem[12960 + (((t) * 64 + (n)) * 40) + (k)]
  const int tid = threadIdx.x, b = blockIdx.z, ocg = blockIdx.y;
  const int tileY = blockIdx.x >> 3, tileX = blockIdx.x & 7;
  const int h0 = tileY * 16 - 1, w0 = tileX * 16 - 1;
  const int wave = tid >> 6, lane = tid & 63, m16 = lane & 15, quad = lane >> 4;

  f32x4 acc[4][4];
#pragma unroll
  for (int i = 0; i < 4; ++i)
#pragma unroll
    for (int j = 0; j < 4; ++j) acc[i][j] = f32x4{0.f, 0.f, 0.f, 0.f};

  for (int kc = 0; kc < NKC; ++kc) {
    if (kc) __syncthreads();
    for (int e = tid; e < 1296; e += 256) {
      int pos = e >> 2, q = e & 3;
      int y = pos / 18, x = pos - y * 18;
      int gh = h0 + y, gw = w0 + x;
      uint4 v = uint4{0u, 0u, 0u, 0u};
      if ((unsigned)gh < 128u && (unsigned)gw < 128u)
        v = *(const uint4*)(in + ((size_t)((b << 14) + (gh << 7) + gw)) * ICH + kc * 32 + q * 8);
      *(uint4*)&SHX(pos, q * 8) = v;
    }
    const uint4* wsrc = (const uint4*)(wb + ((size_t)(ocg * NKC + kc)) * 9 * 64 * 32);
    for (int e = tid; e < 2304; e += 256) {
      int q = e & 3, n = (e >> 2) & 63, t = e >> 8;
      *(uint4*)&SWX(t, n, q * 8) = wsrc[e];
    }
    __syncthreads();
#pragma unroll
    for (int t = 0; t < 9; ++t) {
      const int dy = t / 3, dx = t - dy * 3;
      bf16x8 bfr[4];
#pragma unroll
      for (int nt = 0; nt < 4; ++nt)
        bfr[nt] = *(const bf16x8*)&SWX(t, nt * 16 + m16, quad * 8);
#pragma unroll
      for (int mi = 0; mi < 4; ++mi) {
        const int py = wave * 4 + mi;
        const bf16x8 afr = *(const bf16x8*)&SHX((py + dy) * 18 + dx + m16, quad * 8);
#pragma unroll
        for (int nt = 0; nt < 4; ++nt)
          acc[mi][nt] = __builtin_amdgcn_mfma_f32_16x16x32_bf16(afr, bfr[nt], acc[mi][nt], 0, 0, 0);
      }
    }
  }

  float bv[4];
#pragma unroll
  for (int nt = 0; nt < 4; ++nt) bv[nt] = bias[ocg * 64 + nt * 16 + m16];

  if constexpr (GATE) {
    // stage bf16-quantized ReLU'd fragments into LDS overlay sG[256 px][68]
    __syncthreads();   // all MFMA smem reads done
    __hip_bfloat16* sG = smem;
#pragma unroll
    for (int mi = 0; mi < 4; ++mi)
#pragma unroll
      for (int nt = 0; nt < 4; ++nt) {
        const int och = nt * 16 + m16;
#pragma unroll
        for (int r = 0; r < 4; ++r) {
          const int p = (wave * 4 + mi) * 16 + quad * 4 + r;
          sG[p * 68 + och] = f2bf(fmaxf(acc[mi][nt][r] + bv[nt], 0.f));
        }
      }
    __syncthreads();
    // per-thread gate2: pixel p = tid
    const int p = tid;
    float a6[6];
#pragma unroll
    for (int k = 0; k < 6; ++k) a6[k] = b_g2[k];
#pragma unroll
    for (int i8 = 0; i8 < 8; ++i8) {
      const bf16x8 v8 = *(const bf16x8*)&sG[p * 68 + i8 * 8];
#pragma unroll
      for (int j = 0; j < 8; ++j) {
        const float v = bf2f(((const __hip_bfloat16*)&v8)[j]);
#pragma unroll
        for (int k = 0; k < 6; ++k)
          a6[k] = fmaf(wg2[k * 64 + i8 * 8 + j], v, a6[k]);
      }
    }
    const int lab = labels[b];
    float gate[6], gl = 0.f;
#pragma unroll
    for (int k = 0; k < 6; ++k) {
      gate[k] = 1.f / (1.f + __expf(-a6[k]));
      gl = (k == lab) ? gate[k] : gl;
    }
    const float civ = ci[lab];
    const float it = gl * civ;
    const int h = tileY * 16 + (p >> 4), w = tileX * 16 + (p & 15);
    const int pix = (h << 7) + w;
#pragma unroll
    for (int k = 0; k < 6; ++k)
      out_cg[((b * 6 + k) << 14) + pix] = (k == lab) ? gate[k] : 0.f;
    inten[(b << 14) + pix] = it;
    out_cond[(b << 14) + pix] = it * gl;
    return;
  }

#pragma unroll
  for (int mi = 0; mi < 4; ++mi) {
    const int py = wave * 4 + mi;
    const int h = tileY * 16 + py;
    const int chc = (h == 0) ? 0 : ((h == 127) ? 2 : 1);
#pragma unroll
    for (int nt = 0; nt < 4; ++nt) {
      float sr0 = 0.f, sr1 = 0.f, sr2 = 0.f;
      if constexpr (ADD_SS) {
        const float* sp = SS + ((size_t)(b << 8) + (ocg * 64 + nt * 16 + m16)) * 9;
        sr0 = sp[chc * 3 + 0]; sr1 = sp[chc * 3 + 1]; sr2 = sp[chc * 3 + 2];
      }
      const int och = ocg * 64 + nt * 16 + m16;
#pragma unroll
      for (int r = 0; r < 4; ++r) {
        const int px = quad * 4 + r;
        const int w = tileX * 16 + px;
        float v = acc[mi][nt][r] + bv[nt];
        if constexpr (ADD_SS)
          v += (w == 0) ? sr0 : ((w == 127) ? sr2 : sr1);
        v = fmaxf(v, 0.f);
        out[((size_t)((b << 14) + (h << 7) + w)) * och_total + och] = f2bf(v);
      }
    }
  }
#undef SHX
#undef SWX
}

// ---------------- fused GEMM+softmax, v8: async global_load_lds A-staging ----------------
// R15 post-mortem: coalesced stores were neutral -> residual is staging VALU + mem
// stalls. v8 stages W2 via global_load_lds DMA (16 B/lane, wave-uniform base +
// lane*16 layout holds by construction) -> no VGPR round-trip; DMA overlaps the
// 32 MFMA; barrier at unit end drains vmcnt.
__global__ __launch_bounds__(256, 3) void gemm_softmax_kernel(
    const __hip_bfloat16* __restrict__ f1, const __hip_bfloat16* __restrict__ w2b,
    const float* __restrict__ b_f2, const float* __restrict__ inten,
    __hip_bfloat16* __restrict__ wout)
{
  __shared__ __hip_bfloat16 sW[2][8192];       // 2 x 16 KB: [mtl2][ks8][lane64][8]
  __shared__ __hip_bfloat16 sT[49][136];       // softmax out: [tap][pix] (+8 pad)
  const int tid = threadIdx.x;
  const int pix0 = blockIdx.x * 128;
  const int c0 = blockIdx.y * 8;                 // 8 channels per block
  const int wave = tid >> 6, lane = tid & 63;
  const int n16 = lane & 15, quad = lane >> 4;
  const int p0 = pix0 + wave * 16 + n16;         // pixel group 0
  const int p1 = p0 + 64;                        // pixel group 1

  // B fragments (f1, channel-invariant): 2 pixel groups x 8 ks-steps (64 VGPR)
  bf16x8 bfr0[8], bfr1[8];
#pragma unroll
  for (int ks = 0; ks < 8; ++ks) {
    bfr0[ks] = *(const bf16x8*)(f1 + (size_t)p0 * 256 + ks * 32 + quad * 8);
    bfr1[ks] = *(const bf16x8*)(f1 + (size_t)p1 * 256 + ks * 32 + quad * 8);
  }

  const float s0v = inten[p0], s1v = inten[p1];
  const int ob = pix0 >> 14, op = pix0 & 16383;

  // unit u (0..15) = channel c0+(u>>1), mt-pair (u&1): 16 KB at w2b + unit<<12 elems
#define W2U(u) ((const uint4*)(w2b + ((((size_t)c0 + ((u) >> 1)) * 4 + (((u) & 1) << 1)) << 12)))

  // prologue: DMA unit 0 into buf 0
  {
    const uint4* s0 = W2U(0);
    uint4* d0 = (uint4*)&sW[0][0];
#pragma unroll
    for (int j = 0; j < 4; ++j)
      gld_lds16(s0 + tid + j * 256, d0 + tid + j * 256);
  }
  __syncthreads();

#pragma unroll 1
  for (int cl = 0; cl < 8; ++cl) {
    const int c = c0 + cl;
    f32x4 ac0[4], ac1[4];
#pragma unroll
    for (int mt = 0; mt < 4; ++mt) { ac0[mt] = f32x4{0.f,0.f,0.f,0.f}; ac1[mt] = f32x4{0.f,0.f,0.f,0.f}; }

#pragma unroll
    for (int h = 0; h < 2; ++h) {
      const int u = cl * 2 + h;
      // DMA prefetch of unit u+1 into the other buffer (overlaps the MFMA below;
      // buffer is dead: its last readers finished before the barrier ending iter u-1)
      {
        const uint4* sn = W2U(u < 15 ? u + 1 : 15);
        uint4* dn = (uint4*)&sW[(u + 1) & 1][0];
#pragma unroll
        for (int j = 0; j < 4; ++j)
          gld_lds16(sn + tid + j * 256, dn + tid + j * 256);
      }

      // compute unit u (mt = 2h, 2h+1) from buf (u&1): 32 MFMA
      const __hip_bfloat16* bufp = &sW[u & 1][0];
#pragma unroll
      for (int ks = 0; ks < 8; ++ks) {
        const bf16x8 a0 = *(const bf16x8*)(bufp + ((ks) * 64 + lane) * 8);
        const bf16x8 a1 = *(const bf16x8*)(bufp + ((8 + ks) * 64 + lane) * 8);
        ac0[h * 2 + 0] = __builtin_amdgcn_mfma_f32_16x16x32_bf16(a0, bfr0[ks], ac0[h * 2 + 0], 0, 0, 0);
        ac1[h * 2 + 0] = __builtin_amdgcn_mfma_f32_16x16x32_bf16(a0, bfr1[ks], ac1[h * 2 + 0], 0, 0, 0);
        ac0[h * 2 + 1] = __builtin_amdgcn_mfma_f32_16x16x32_bf16(a1, bfr0[ks], ac0[h * 2 + 1], 0, 0, 0);
        ac1[h * 2 + 1] = __builtin_amdgcn_mfma_f32_16x16x32_bf16(a1, bfr1[ks], ac1[h * 2 + 1], 0, 0, 0);
      }
      __syncthreads();   // drains DMA (vmcnt) + fences buffer swap
    }

    // softmax per pixel group (in-place in ac*), results -> sT
#pragma unroll
    for (int g = 0; g < 2; ++g) {
      f32x4* ac = g ? ac1 : ac0;
      const float s = g ? s1v : s0v;
      float mx = -3.4e38f;
#pragma unroll
      for (int mt = 0; mt < 4; ++mt)
#pragma unroll
        for (int r = 0; r < 4; ++r) {
          const int tap = mt * 16 + quad * 4 + r;
          const bool ok = tap < 49;
          const float lv = ok ? (ac[mt][r] + b_f2[c * 49 + (ok ? tap : 0)]) * s : -3.4e38f;
          ac[mt][r] = lv;
          mx = fmaxf(mx, lv);
        }
      mx = fmaxf(mx, __shfl_xor(mx, 16, 64));
      mx = fmaxf(mx, __shfl_xor(mx, 32, 64));
      float sum = 0.f;
#pragma unroll
      for (int mt = 0; mt < 4; ++mt)
#pragma unroll
        for (int r = 0; r < 4; ++r) {
          const float e = __expf(ac[mt][r] - mx);   // invalid taps: exp(-inf)=0
          ac[mt][r] = e;
          sum += e;
        }
      sum += __shfl_xor(sum, 16, 64);
      sum += __shfl_xor(sum, 32, 64);
      const float rs = 1.f / sum;

      const int px = wave * 16 + n16 + g * 64;
#pragma unroll
      for (int mt = 0; mt < 4; ++mt)
#pragma unroll
        for (int r = 0; r < 4; ++r) {
          const int tap = mt * 16 + quad * 4 + r;
          if (tap < 49) sT[tap][px] = f2bf(ac[mt][r] * rs);
        }
    }
    __syncthreads();   // sT visible

    // cooperative coalesced store: 49 taps x 128 px = 784 uint4
    __hip_bfloat16* wob = wout + (((size_t)(ob * 24 + c) * 49) << 14) + op;
    for (int e = tid; e < 784; e += 256) {
      const int tap = e >> 4, qq = e & 15;
      *(uint4*)(wob + ((size_t)tap << 14) + qq * 8) = *(const uint4*)&sT[tap][qq * 8];
    }
    // WAR on sT protected by the next channel's h-loop barriers
  }
#undef W2U
}

// ---------------- diffusion step v2: 4 pixels/thread, vectorized wt loads ----------------
__global__ __launch_bounds__(256) void diff_kernel(
    const float* __restrict__ lin, const __hip_bfloat16* __restrict__ wts,
    float* __restrict__ lout)
{
  __shared__ float sT[14][136];   // 8+6 rows, 128+6 cols (136: row 16B-aligned)
  const int bc = blockIdx.y;
  const int h0 = blockIdx.x * 8;
  const int tid = threadIdx.x;
  for (int e = tid; e < 14 * 134; e += 256) {
    int y = e / 134, x = e - y * 134;
    int gh = min(max(h0 - 3 + y, 0), 127), gw = min(max(x - 3, 0), 127);
    sT[y][x] = lin[(bc << 14) + (gh << 7) + gw];
  }
  __syncthreads();
  const int tw = (tid & 31) * 4;   // first of 4 pixels in w
  const int ty = tid >> 5;         // row 0..7
  const int h = h0 + ty;
  const __hip_bfloat16* wp = wts + (((size_t)bc * 49) << 14) + (h << 7) + tw;
  float a0 = 0.f, a1 = 0.f, a2 = 0.f, a3 = 0.f;
#pragma unroll
  for (int kh = 0; kh < 7; ++kh) {
    const float* row = &sT[ty + kh][tw];
    float r[12];
    *(f32x4*)&r[0] = *(const f32x4*)(row);
    *(f32x4*)&r[4] = *(const f32x4*)(row + 4);
    *(f32x4*)&r[8] = *(const f32x4*)(row + 8);
#pragma unroll
    for (int kw = 0; kw < 7; ++kw) {
      const int t = kh * 7 + kw;
      const uint2 wq = *(const uint2*)(wp + ((size_t)t << 14));
      a0 = fmaf(bflo(wq.x), r[kw],     a0);
      a1 = fmaf(bfhi(wq.x), r[kw + 1], a1);
      a2 = fmaf(bflo(wq.y), r[kw + 2], a2);
      a3 = fmaf(bfhi(wq.y), r[kw + 3], a3);
    }
  }
  *(f32x4*)(lout + (bc << 14) + (h << 7) + tw) = f32x4{a0, a1, a2, a3};
}

// ---------------- orchestration ----------------
extern "C" void kernel_launch(void* const* d_in, const int* in_sizes, int n_in,
                              void* d_out, int out_size, void* d_ws, size_t ws_size,
                              hipStream_t stream)
{
  const float* depth = (const float*)d_in[0];
  const float* texf  = (const float*)d_in[1];
  const int*   labels= (const int*)d_in[2];
  const float* w_te1 = (const float*)d_in[3];
  const float* b_te1 = (const float*)d_in[4];
  const float* w_te2 = (const float*)d_in[5];
  const float* b_te2 = (const float*)d_in[6];
  const float* emb   = (const float*)d_in[7];
  const float* w_f1  = (const float*)d_in[8];
  const float* b_f1  = (const float*)d_in[9];
  const float* w_f2  = (const float*)d_in[10];
  const float* b_f2  = (const float*)d_in[11];
  const float* w_g1  = (const float*)d_in[12];
  const float* b_g1  = (const float*)d_in[13];
  const float* w_g2  = (const float*)d_in[14];
  const float* b_g2  = (const float*)d_in[15];
  const float* ci    = (const float*)d_in[16];

  char*  ws  = (char*)d_ws;
  float* wsf = (float*)d_ws;
  __hip_bfloat16* w2bf  = (__hip_bfloat16*)(ws + BO_W2B);
  __hip_bfloat16* te2bf = (__hip_bfloat16*)(ws + BO_TE2B);
  __hip_bfloat16* g1bf  = (__hip_bfloat16*)(ws + BO_WG1B);
  __hip_bfloat16* f1bf  = (__hip_bfloat16*)(ws + BO_WF1B);
  __hip_bfloat16* tex   = (__hip_bfloat16*)(ws + BO_TEX);
  __hip_bfloat16* f1    = (__hip_bfloat16*)(ws + BO_F1);
  float* ping           = (float*)(ws + BO_PING);
  float* pong           = (float*)(ws + BO_PONG);
  __hip_bfloat16* wts   = (__hip_bfloat16*)(ws + BO_W);
  __hip_bfloat16* t1    = (__hip_bfloat16*)(ws + BO_T1);

  float* out      = (float*)d_out;
  float* out_enh  = out;                 // [4][24][128][128]
  float* out_cg   = out + 1572864;       // [4][6][128][128]
  float* out_cond = out + 1966080;       // [4][1][128][128]

  prep_kernel<<<512, 256, 0, stream>>>(w_te1, w_te2, w_g1, w_f1, w_f2, w_g2, emb, labels, wsf);
  conv3x3_kernel<float, 3, true><<<dim3(64, 2, 4), 256, 0, stream>>>(texf, wsf + O_WTE1, b_te1, t1, 64);
  conv3x3_mfma_kernel<64,  false, false><<<dim3(64, 2, 4), 256, 0, stream>>>(
      t1, te2bf, b_te2, nullptr, tex, 128,
      nullptr, nullptr, nullptr, nullptr, nullptr, nullptr, nullptr);
  // gate1 conv + fused gate2
  conv3x3_mfma_kernel<128, false, true><<<dim3(64, 1, 4), 256, 0, stream>>>(
      tex, g1bf, b_g1, nullptr, nullptr, 64,
      wsf + O_WG2, b_g2, labels, ci, out_cg, out_cond, wsf + O_INT);
  conv3x3_mfma_kernel<128, true, false><<<dim3(64, 4, 4), 256, 0, stream>>>(
      tex, f1bf, b_f1, wsf + O_SS, f1, 256,
      nullptr, nullptr, nullptr, nullptr, nullptr, nullptr, nullptr);
  gemm_softmax_kernel<<<dim3(512, 3), 256, 0, stream>>>(f1, w2bf, b_f2, wsf + O_INT, wts);

  dim3 dgrid(16, 96);
  diff_kernel<<<dgrid, 256, 0, stream>>>(depth, wts, ping);
  diff_kernel<<<dgrid, 256, 0, stream>>>(ping, wts, pong);
  diff_kernel<<<dgrid, 256, 0, stream>>>(pong, wts, ping);
  diff_kernel<<<dgrid, 256, 0, stream>>>(ping, wts, pong);
  diff_kernel<<<dgrid, 256, 0, stream>>>(pong, wts, ping);
  diff_kernel<<<dgrid, 256, 0, stream>>>(ping, wts, pong);
  diff_kernel<<<dgrid, 256, 0, stream>>>(pong, wts, ping);
  diff_kernel<<<dgrid, 256, 0, stream>>>(ping, wts, out_enh);
}